// Round 8
// baseline (2790.343 us; speedup 1.0000x reference)
//
#include <hip/hip_runtime.h>
#include <hip/hip_bf16.h>
#include <cstdint>

#define B_   4
#define N_   8192
#define NP_  2048
#define NS_  32
#define CIN_ 64
#define M_   (B_*NP_*NS_)   // 262144 rows
#define EPS_ 1e-5f
#define R2_  0.01f          // d2 <= 0.01f  <=>  d2 < float64(0.1*0.1)

typedef unsigned long long ull;
typedef float v2f __attribute__((ext_vector_type(2)));

// ---------------- feature transpose: (B,CIN,N) f32 -> (B,N,CIN) bf16 ----------------
__global__ __launch_bounds__(256) void transpose_kernel(const float* __restrict__ feat,
                                                        __hip_bfloat16* __restrict__ featT)
{
    __shared__ float tile[64][65];
    const int b  = blockIdx.y;
    const int j0 = blockIdx.x * 64;
    const int tx = threadIdx.x & 63, ty = threadIdx.x >> 6;
    for (int cc = ty; cc < 64; cc += 4)
        tile[tx][cc] = feat[((size_t)(b*CIN_ + cc))*N_ + j0 + tx];
    __syncthreads();
    for (int cc = ty; cc < 64; cc += 4)
        featT[((size_t)(b*N_ + j0 + cc))*64 + tx] = __float2bfloat16(tile[cc][tx]);
}

// f32 max with DPP neighbor (invalid lanes keep old value -> identity under max)
template<int CTRL>
__device__ __forceinline__ float dppmaxf(float v)
{
    int o = __builtin_amdgcn_update_dpp(__float_as_int(v), __float_as_int(v), CTRL, 0xF, 0xF, false);
    return fmaxf(v, __int_as_float(o));
}

// ---- FPS: 1 block/batch, 512 thr x 16 contiguous pts, ballot winner, reg-sourced coords ----
__global__ __launch_bounds__(512) void fps_kernel(const float* __restrict__ xyz,
    int* __restrict__ fps_idx, float* __restrict__ new_xyzf, float* __restrict__ out)
{
#pragma clang fp contract(off)
    const int b = blockIdx.x;
    const int t = threadIdx.x;
    const float* X = xyz + (size_t)b * N_ * 3;

    __shared__ float wavemax[8];
    __shared__ float slot[3];     // winner coords (written from winner's registers)
    __shared__ int   slotidx;     // winner global index

    // thread t owns contiguous points t*16 .. t*16+15 (global order = w asc, ln asc, j asc)
    v2f px[8], py[8], pz[8], dst[8];
#pragma unroll
    for (int g = 0; g < 8; ++g) {
        const int p0 = t*16 + 2*g, p1 = p0 + 1;
        px[g] = (v2f){X[p0*3+0], X[p1*3+0]};
        py[g] = (v2f){X[p0*3+1], X[p1*3+1]};
        pz[g] = (v2f){X[p0*3+2], X[p1*3+2]};
        dst[g] = (v2f){1e10f, 1e10f};
    }
    const int wv = t >> 6, ln = t & 63;

    float cx = X[0], cy = X[1], cz = X[2];   // first sampled point = index 0
    if (t == 0) {
        fps_idx[b*NP_] = 0;
        size_t o3 = (size_t)(b*NP_) * 3;
        new_xyzf[o3] = cx; new_xyzf[o3+1] = cy; new_xyzf[o3+2] = cz;
        out[o3] = cx; out[o3+1] = cy; out[o3+2] = cz;
    }
    for (int it = 1; it < NP_; ++it) {
        // phase 1: packed distance update + per-thread best VALUE
        float bestv = -1.0f;
        const v2f c0 = (v2f){cx, cx}, c1 = (v2f){cy, cy}, c2 = (v2f){cz, cz};
#pragma unroll
        for (int g = 0; g < 8; ++g) {
            v2f dx = px[g] - c0, dy = py[g] - c1, dz = pz[g] - c2;
            v2f dd = dx*dx;          // contract(off): exact numpy op order per component
            dd = dd + dy*dy;
            dd = dd + dz*dz;
            v2f nd;
            nd.x = fminf(dst[g].x, dd.x);
            nd.y = fminf(dst[g].y, dd.y);
            dst[g] = nd;
            bestv = fmaxf(bestv, nd.x);
            bestv = fmaxf(bestv, nd.y);
        }
        // phase 2: wave max via DPP -> LDS slot per wave
        float wm = bestv;
        wm = dppmaxf<0x111>(wm);
        wm = dppmaxf<0x112>(wm);
        wm = dppmaxf<0x114>(wm);
        wm = dppmaxf<0x118>(wm);
        wm = dppmaxf<0x142>(wm);
        wm = dppmaxf<0x143>(wm);
        if (ln == 63) wavemax[wv] = wm;
        __syncthreads();                       // barrier A
        // all threads: block max + first winning wave (deterministic, register-cached)
        const float v0 = wavemax[0], v1 = wavemax[1], v2 = wavemax[2], v3 = wavemax[3];
        const float v4 = wavemax[4], v5 = wavemax[5], v6 = wavemax[6], v7 = wavemax[7];
        const float bmax = fmaxf(fmaxf(fmaxf(v0, v1), fmaxf(v2, v3)),
                                 fmaxf(fmaxf(v4, v5), fmaxf(v6, v7)));
        int wstar = 7;
        if (v6 == bmax) wstar = 6;
        if (v5 == bmax) wstar = 5;
        if (v4 == bmax) wstar = 4;
        if (v3 == bmax) wstar = 3;
        if (v2 == bmax) wstar = 2;
        if (v1 == bmax) wstar = 1;
        if (v0 == bmax) wstar = 0;
        if (wv == wstar) {                     // wave-uniform branch
            const ull mask = __ballot(bestv == bmax);
            const int lstar = __builtin_ctzll(mask);   // lowest lane == lowest thread id
            if (ln == lstar) {
                int jj = 0; float wx = 0.f, wy = 0.f, wz = 0.f;
#pragma unroll
                for (int g = 7; g >= 0; --g) { // descending: last assignment = smallest j
                    if (dst[g].y == bmax) { jj = 2*g+1; wx = px[g].y; wy = py[g].y; wz = pz[g].y; }
                    if (dst[g].x == bmax) { jj = 2*g;   wx = px[g].x; wy = py[g].x; wz = pz[g].x; }
                }
                slot[0] = wx; slot[1] = wy; slot[2] = wz;
                slotidx = t*16 + jj;
            }
        }
        __syncthreads();                       // barrier B
        cx = slot[0]; cy = slot[1]; cz = slot[2];
        if (t == 0) {
            const int widx = slotidx;
            fps_idx[b*NP_ + it] = widx;
            size_t o3 = ((size_t)(b*NP_ + it)) * 3;
            new_xyzf[o3] = cx; new_xyzf[o3+1] = cy; new_xyzf[o3+2] = cz;
            out[o3] = cx; out[o3+1] = cy; out[o3+2] = cz;
        }
    }
}

// ---------------- ball query: one wave per center ----------------
__global__ __launch_bounds__(256) void ball_kernel(const float* __restrict__ xyz,
    const float* __restrict__ new_xyzf, int* __restrict__ ballidx)
{
#pragma clang fp contract(off)
    const int gw   = (blockIdx.x * 256 + threadIdx.x) >> 6;   // b*NP + p
    const int lane = threadIdx.x & 63;
    const int b    = gw >> 11;                                 // / NP_
    const float* X = xyz + (size_t)b * N_ * 3;
    const float cx = new_xyzf[(size_t)gw*3];
    const float cy = new_xyzf[(size_t)gw*3+1];
    const float cz = new_xyzf[(size_t)gw*3+2];
    int* outp = ballidx + (size_t)gw * NS_;
    int total = 0, first = -1;
    for (int base = 0; base < N_; base += 64) {
        const int j = base + lane;
        float dx = cx - X[j*3], dy = cy - X[j*3+1], dz = cz - X[j*3+2];
        float d2 = dx*dx;
        d2 = d2 + dy*dy;
        d2 = d2 + dz*dz;
        const bool in = d2 <= R2_;   // f64 threshold semantics of the reference
        ull m = __ballot(in);
        if (m) {
            if (first < 0) first = base + __builtin_ctzll(m);
            int r = total + __popcll(m & ((1ull << lane) - 1ull));
            if (in && r < NS_) outp[r] = j;
            total += (int)__popcll(m);
            if (total >= NS_) break;
        }
    }
    if (total < NS_) {
        int f = first < 0 ? 0 : first;
        if (lane >= total && lane < NS_) outp[lane] = f;
    }
}

// ---------------- layer1: fused gather + GEMM (67->64), store pre1 bf16 + stats ----------------
__global__ __launch_bounds__(256) void gemm1_kernel(const float* __restrict__ xyz,
    const __hip_bfloat16* __restrict__ featT, const float* __restrict__ newxyz,
    const int* __restrict__ ballidx, const float* __restrict__ W, const float* __restrict__ bias,
    __hip_bfloat16* __restrict__ pre1, float* __restrict__ psum, float* __restrict__ psumsq)
{
    const int lane = threadIdx.x & 63;
    const int gw   = (blockIdx.x * 256 + threadIdx.x) >> 6;   // 4096 waves
    float w[67];
#pragma unroll
    for (int k = 0; k < 67; ++k) w[k] = W[lane*67 + k];
    const float bs = bias[lane];
    float s1 = 0.f, s2 = 0.f;
    for (int r = gw; r < M_; r += 4096) {
        const int b = r >> 16;            // / (NP_*NS_)
        const int p = (r & 65535) >> 5;   // within-batch point
        const int j = ballidx[r];
        const float* xp = xyz    + ((size_t)b*N_  + j)*3;
        const float* cp = newxyz + ((size_t)b*NP_ + p)*3;
        float acc = bs;
        acc = fmaf(xp[0] - cp[0], w[0], acc);
        acc = fmaf(xp[1] - cp[1], w[1], acc);
        acc = fmaf(xp[2] - cp[2], w[2], acc);
        const unsigned* rp = (const unsigned*)(featT + ((size_t)b*N_ + j)*64);
#pragma unroll
        for (int kk = 0; kk < 32; ++kk) {
            unsigned u = rp[kk];
            float v0 = __uint_as_float(u << 16);
            float v1 = __uint_as_float(u & 0xffff0000u);
            acc = fmaf(v0, w[3 + 2*kk], acc);
            acc = fmaf(v1, w[4 + 2*kk], acc);
        }
        pre1[(size_t)r*64 + lane] = __float2bfloat16(acc);
        s1 += acc;
        s2 = fmaf(acc, acc, s2);
    }
    psum  [(size_t)gw*64 + lane] = s1;
    psumsq[(size_t)gw*64 + lane] = s2;
}

// ---------------- layer2: BN1+ReLU fused input, GEMM 64->64 IN PLACE + stats ----------------
__global__ __launch_bounds__(256) void gemm2_kernel(__hip_bfloat16* __restrict__ buf,
    const float* __restrict__ W, const float* __restrict__ bias,
    const float* __restrict__ bnsc, const float* __restrict__ bnsh,
    float* __restrict__ psum, float* __restrict__ psumsq)
{
    const int lane = threadIdx.x & 63;
    const int gw   = (blockIdx.x * 256 + threadIdx.x) >> 6;   // 4096 waves
    __shared__ float ssc[64], ssh[64];
    if (threadIdx.x < 64) { ssc[threadIdx.x] = bnsc[threadIdx.x]; ssh[threadIdx.x] = bnsh[threadIdx.x]; }
    __syncthreads();
    float w[64];
#pragma unroll
    for (int k = 0; k < 64; ++k) w[k] = W[lane*64 + k];
    const float bs = bias[lane];
    float s1 = 0.f, s2 = 0.f;
    for (int r = gw; r < M_; r += 4096) {
        const unsigned* rp = (const unsigned*)(buf + (size_t)r*64);
        float acc = bs;
#pragma unroll
        for (int kk = 0; kk < 32; ++kk) {
            unsigned u = rp[kk];
            float v0 = __uint_as_float(u << 16);
            float v1 = __uint_as_float(u & 0xffff0000u);
            v0 = fmaxf(fmaf(v0, ssc[2*kk],   ssh[2*kk]),   0.f);
            v1 = fmaxf(fmaf(v1, ssc[2*kk+1], ssh[2*kk+1]), 0.f);
            acc = fmaf(v0, w[2*kk],   acc);
            acc = fmaf(v1, w[2*kk+1], acc);
        }
        buf[(size_t)r*64 + lane] = __float2bfloat16(acc);   // in-place: row read fully above
        s1 += acc;
        s2 = fmaf(acc, acc, s2);
    }
    psum  [(size_t)gw*64 + lane] = s1;
    psumsq[(size_t)gw*64 + lane] = s2;
}

// ---------------- layer3: BN2+ReLU fused input, GEMM 64->128, fused per-point max/min ----------------
__global__ __launch_bounds__(256) void gemm3_kernel(const __hip_bfloat16* __restrict__ pre2,
    const float* __restrict__ W, const float* __restrict__ bias,
    const float* __restrict__ bnsc, const float* __restrict__ bnsh,
    float* __restrict__ mxb, float* __restrict__ mnb,
    float* __restrict__ psum, float* __restrict__ psumsq)
{
    const int lane = threadIdx.x & 63;
    const int gw   = (blockIdx.x * 256 + threadIdx.x) >> 6;   // 16384 waves
    const int pt   = gw >> 1;           // 8192 points
    const int half = gw & 1;
    __shared__ float ssc[64], ssh[64];
    if (threadIdx.x < 64) { ssc[threadIdx.x] = bnsc[threadIdx.x]; ssh[threadIdx.x] = bnsh[threadIdx.x]; }
    __syncthreads();
    const int o = half*64 + lane;
    float w[64];
#pragma unroll
    for (int k = 0; k < 64; ++k) w[k] = W[o*64 + k];
    const float bs = bias[o];
    float s1 = 0.f, s2 = 0.f, mx = -1e30f, mn = 1e30f;
    for (int s = 0; s < NS_; ++s) {
        const size_t r = (size_t)pt*NS_ + s;
        const unsigned* rp = (const unsigned*)(pre2 + r*64);
        float acc = bs;
#pragma unroll
        for (int kk = 0; kk < 32; ++kk) {
            unsigned u = rp[kk];
            float v0 = __uint_as_float(u << 16);
            float v1 = __uint_as_float(u & 0xffff0000u);
            v0 = fmaxf(fmaf(v0, ssc[2*kk],   ssh[2*kk]),   0.f);
            v1 = fmaxf(fmaf(v1, ssc[2*kk+1], ssh[2*kk+1]), 0.f);
            acc = fmaf(v0, w[2*kk],   acc);
            acc = fmaf(v1, w[2*kk+1], acc);
        }
        s1 += acc;
        s2 = fmaf(acc, acc, s2);
        mx = fmaxf(mx, acc);
        mn = fminf(mn, acc);
    }
    mxb[(size_t)pt*128 + o] = mx;
    mnb[(size_t)pt*128 + o] = mn;
    psum  [(size_t)pt*128 + o] = s1;
    psumsq[(size_t)pt*128 + o] = s2;
}

// ---------------- deterministic BN stat reduce -> scale/shift ----------------
template<int CO>
__global__ __launch_bounds__(256) void bnred_kernel(const float* __restrict__ psum,
    const float* __restrict__ psumsq, const float* __restrict__ g, const float* __restrict__ beta,
    float* __restrict__ sc, float* __restrict__ sh, int nslots)
{
    const int c = blockIdx.x;
    const int t = threadIdx.x;
    float s1 = 0, s2 = 0;
    for (int i = t; i < nslots; i += 256) {
        s1 += psum  [(size_t)i*CO + c];
        s2 += psumsq[(size_t)i*CO + c];
    }
    __shared__ float a1[256], a2[256];
    a1[t] = s1; a2[t] = s2;
    __syncthreads();
    for (int st = 128; st > 0; st >>= 1) {
        if (t < st) { a1[t] += a1[t+st]; a2[t] += a2[t+st]; }
        __syncthreads();
    }
    if (t == 0) {
        const float invM = 1.0f / (float)M_;
        float mu  = a1[0] * invM;
        float var = fmaxf(a2[0] * invM - mu*mu, 0.f);
        float rs  = 1.0f / sqrtf(var + EPS_);
        float s   = rs * g[c];
        sc[c] = s;
        sh[c] = fmaf(-mu, s, beta[c]);
    }
}

// ---------------- BN3 affine on max/min + ReLU, LDS transpose, write (B,128,NP) f32 ----------------
__global__ __launch_bounds__(256) void final_kernel(const float* __restrict__ mxb,
    const float* __restrict__ mnb, const float* __restrict__ sc, const float* __restrict__ sh,
    float* __restrict__ out)
{
    __shared__ float tile[128][65];
    const int b = blockIdx.y, p0 = blockIdx.x * 64;
    {
        const int o = threadIdx.x & 127, ph = threadIdx.x >> 7;
        const float s = sc[o], h = sh[o];
        const bool pos = (s >= 0.f);
        for (int pl = ph; pl < 64; pl += 2) {
            const size_t pt = (size_t)b*NP_ + p0 + pl;
            float v = pos ? mxb[pt*128 + o] : mnb[pt*128 + o];
            tile[o][pl] = fmaxf(fmaf(v, s, h), 0.f);   // max_s relu(affine) == relu(affine(max/min))
        }
    }
    __syncthreads();
    {
        const int p = threadIdx.x & 63, oh = threadIdx.x >> 6;
        for (int oo = oh; oo < 128; oo += 4)
            out[(size_t)(B_*NP_*3) + ((size_t)(b*128 + oo))*NP_ + p0 + p] = tile[oo][p];
    }
}

// ---------------- launch ----------------
extern "C" void kernel_launch(void* const* d_in, const int* in_sizes, int n_in,
                              void* d_out, int out_size, void* d_ws, size_t ws_size,
                              hipStream_t stream)
{
    const float* xyz  = (const float*)d_in[0];
    const float* feat = (const float*)d_in[1];
    const float* W0   = (const float*)d_in[2];
    const float* b0   = (const float*)d_in[3];
    const float* g0   = (const float*)d_in[4];
    const float* be0  = (const float*)d_in[5];
    const float* W1   = (const float*)d_in[6];
    const float* b1   = (const float*)d_in[7];
    const float* g1   = (const float*)d_in[8];
    const float* be1  = (const float*)d_in[9];
    const float* W2   = (const float*)d_in[10];
    const float* b2   = (const float*)d_in[11];
    const float* g2   = (const float*)d_in[12];
    const float* be2  = (const float*)d_in[13];

    char* ws = (char*)d_ws;                                  // total needed: ~53.1 MB
    int*   fpsidx = (int*)  (ws + 0);                        //  32 KB
    float* newxyz = (float*)(ws + 32768);                    //  96 KB
    int*   ball   = (int*)  (ws + 131072);                   //   1 MB
    float* scb    = (float*)(ws + 1179648);                  //   4 KB
    float* psum   = (float*)(ws + 1183744);                  //   4 MB
    float* psumsq = (float*)(ws + 5378048);                  //   4 MB
    __hip_bfloat16* featT = (__hip_bfloat16*)(ws + 9572352); //   4 MB
    float* mxb    = (float*)(ws + 13766656);                 //   4 MB
    float* mnb    = (float*)(ws + 17960960);                 //   4 MB
    __hip_bfloat16* buf1 = (__hip_bfloat16*)(ws + 22155264); //  32 MB (pre1, then pre2 in place)
    float* out = (float*)d_out;                              // reference outputs are float32

    float* sc1 = scb;       float* sh1 = scb + 128;
    float* sc2 = scb + 256; float* sh2 = scb + 384;
    float* sc3 = scb + 512; float* sh3 = scb + 640;

    transpose_kernel<<<dim3(N_/64, B_), 256, 0, stream>>>(feat, featT);
    fps_kernel<<<dim3(B_), 512, 0, stream>>>(xyz, fpsidx, newxyz, out);
    ball_kernel<<<dim3(B_*NP_/4), 256, 0, stream>>>(xyz, newxyz, ball);

    gemm1_kernel<<<1024, 256, 0, stream>>>(xyz, featT, newxyz, ball, W0, b0, buf1, psum, psumsq);
    bnred_kernel<64><<<64, 256, 0, stream>>>(psum, psumsq, g0, be0, sc1, sh1, 4096);
    gemm2_kernel<<<1024, 256, 0, stream>>>(buf1, W1, b1, sc1, sh1, psum, psumsq);
    bnred_kernel<64><<<64, 256, 0, stream>>>(psum, psumsq, g1, be1, sc2, sh2, 4096);
    gemm3_kernel<<<4096, 256, 0, stream>>>(buf1, W2, b2, sc2, sh2, mxb, mnb, psum, psumsq);
    bnred_kernel<128><<<128, 256, 0, stream>>>(psum, psumsq, g2, be2, sc3, sh3, 8192);
    final_kernel<<<dim3(NP_/64, B_), 256, 0, stream>>>(mxb, mnb, sc3, sh3, out);
}

// Round 9
// 2742.114 us; speedup vs baseline: 1.0176x; 1.0176x over previous
//
#include <hip/hip_runtime.h>
#include <hip/hip_bf16.h>
#include <cstdint>

#define B_   4
#define N_   8192
#define NP_  2048
#define NS_  32
#define CIN_ 64
#define M_   (B_*NP_*NS_)   // 262144 rows
#define EPS_ 1e-5f
#define R2_  0.01f          // d2 <= 0.01f  <=>  d2 < float64(0.1*0.1)

typedef unsigned long long ull;
typedef float v2f __attribute__((ext_vector_type(2)));

// ---------------- feature transpose: (B,CIN,N) f32 -> (B,N,CIN) bf16 ----------------
__global__ __launch_bounds__(256) void transpose_kernel(const float* __restrict__ feat,
                                                        __hip_bfloat16* __restrict__ featT)
{
    __shared__ float tile[64][65];
    const int b  = blockIdx.y;
    const int j0 = blockIdx.x * 64;
    const int tx = threadIdx.x & 63, ty = threadIdx.x >> 6;
    for (int cc = ty; cc < 64; cc += 4)
        tile[tx][cc] = feat[((size_t)(b*CIN_ + cc))*N_ + j0 + tx];
    __syncthreads();
    for (int cc = ty; cc < 64; cc += 4)
        featT[((size_t)(b*N_ + j0 + cc))*64 + tx] = __float2bfloat16(tile[cc][tx]);
}

// f32 max with DPP neighbor (invalid lanes keep old value -> identity under max)
template<int CTRL>
__device__ __forceinline__ float dppmaxf(float v)
{
    int o = __builtin_amdgcn_update_dpp(__float_as_int(v), __float_as_int(v), CTRL, 0xF, 0xF, false);
    return fmaxf(v, __int_as_float(o));
}
// u32 max with DPP neighbor
template<int CTRL>
__device__ __forceinline__ unsigned dppmaxu(unsigned v)
{
    unsigned o = (unsigned)__builtin_amdgcn_update_dpp((int)v, (int)v, CTRL, 0xF, 0xF, false);
    return v > o ? v : o;
}

// ---- FPS: 1 block/batch, 512 thr x 16 pts (strided pairs), ONE barrier/iter ----
__global__ __launch_bounds__(512) void fps_kernel(const float* __restrict__ xyz,
    int* __restrict__ fps_idx, float* __restrict__ new_xyzf, float* __restrict__ out)
{
#pragma clang fp contract(off)
    const int b = blockIdx.x;
    const int t = threadIdx.x;
    const float* X = xyz + (size_t)b * N_ * 3;

    __shared__ float xs[N_], ys[N_], zs[N_];   // 96 KB SoA copy of this batch's xyz
    __shared__ ull slots[2][8];                // parity x wave: {wm_bits<<32 | nin}

    for (int p = t; p < N_; p += 512) {
        xs[p] = X[p*3+0]; ys[p] = X[p*3+1]; zs[p] = X[p*3+2];
    }
    // 16 points per thread, strided pairs (2g*512+t, (2g+1)*512+t)
    v2f px[8], py[8], pz[8], dst[8];
#pragma unroll
    for (int g = 0; g < 8; ++g) {
        const int p0 = (2*g)*512 + t, p1 = (2*g+1)*512 + t;
        px[g] = (v2f){X[p0*3+0], X[p1*3+0]};
        py[g] = (v2f){X[p0*3+1], X[p1*3+1]};
        pz[g] = (v2f){X[p0*3+2], X[p1*3+2]};
        dst[g] = (v2f){1e10f, 1e10f};
    }
    const int wv = t >> 6, ln = t & 63;

    float cx = X[0], cy = X[1], cz = X[2];   // first sampled point = index 0
    if (t == 0) {
        fps_idx[b*NP_] = 0;
        size_t o3 = (size_t)(b*NP_) * 3;
        new_xyzf[o3] = cx; new_xyzf[o3+1] = cy; new_xyzf[o3+2] = cz;
        out[o3] = cx; out[o3+1] = cy; out[o3+2] = cz;
    }
    __syncthreads();                           // SoA ready
    for (int it = 1; it < NP_; ++it) {
        const int par = it & 1;
        // phase 1: packed distance update + per-thread best VALUE (pk max)
        v2f bm = (v2f){-1.0f, -1.0f};
        const v2f c0 = (v2f){cx, cx}, c1 = (v2f){cy, cy}, c2 = (v2f){cz, cz};
#pragma unroll
        for (int g = 0; g < 8; ++g) {
            v2f dx = px[g] - c0, dy = py[g] - c1, dz = pz[g] - c2;
            v2f dd = dx*dx;          // contract(off): exact numpy op order per component
            dd = dd + dy*dy;
            dd = dd + dz*dz;
            v2f nd;
            nd.x = fminf(dst[g].x, dd.x);
            nd.y = fminf(dst[g].y, dd.y);
            dst[g] = nd;
            bm.x = fmaxf(bm.x, nd.x);
            bm.y = fmaxf(bm.y, nd.y);
        }
        const float bestv = fmaxf(bm.x, bm.y);
        // wave value-max via DPP -> lane 63 -> SGPR broadcast
        float wm = bestv;
        wm = dppmaxf<0x111>(wm);
        wm = dppmaxf<0x112>(wm);
        wm = dppmaxf<0x114>(wm);
        wm = dppmaxf<0x118>(wm);
        wm = dppmaxf<0x142>(wm);
        wm = dppmaxf<0x143>(wm);
        const float wm_b = __int_as_float(__builtin_amdgcn_readlane(__float_as_int(wm), 63));
        // index recovery (tying lanes only, index-only rescan), then wave u32-max of ~idx
        unsigned nin = 0u;
        if (bestv == wm_b) {
#pragma unroll
            for (int g = 7; g >= 0; --g) {     // descending: last assignment = smallest index
                if (dst[g].y == wm_b) nin = ~(unsigned)((2*g+1)*512 + t);
                if (dst[g].x == wm_b) nin = ~(unsigned)((2*g)*512 + t);
            }
        }
        nin = dppmaxu<0x111>(nin);
        nin = dppmaxu<0x112>(nin);
        nin = dppmaxu<0x114>(nin);
        nin = dppmaxu<0x118>(nin);
        nin = dppmaxu<0x142>(nin);
        nin = dppmaxu<0x143>(nin);
        if (ln == 63) slots[par][wv] = ((ull)__float_as_uint(wm_b) << 32) | nin;
        __syncthreads();                       // the ONLY barrier per iteration
        // all threads: pick block winner from the 8 wave slots (broadcast reads)
        const ull s0 = slots[par][0], s1 = slots[par][1], s2 = slots[par][2], s3 = slots[par][3];
        const ull s4 = slots[par][4], s5 = slots[par][5], s6 = slots[par][6], s7 = slots[par][7];
        const float w0 = __uint_as_float((unsigned)(s0 >> 32)), w1 = __uint_as_float((unsigned)(s1 >> 32));
        const float w2 = __uint_as_float((unsigned)(s2 >> 32)), w3 = __uint_as_float((unsigned)(s3 >> 32));
        const float w4 = __uint_as_float((unsigned)(s4 >> 32)), w5 = __uint_as_float((unsigned)(s5 >> 32));
        const float w6 = __uint_as_float((unsigned)(s6 >> 32)), w7 = __uint_as_float((unsigned)(s7 >> 32));
        const float bmax = fmaxf(fmaxf(fmaxf(w0, w1), fmaxf(w2, w3)),
                                 fmaxf(fmaxf(w4, w5), fmaxf(w6, w7)));
        unsigned m0 = (w0 == bmax) ? (unsigned)s0 : 0u;
        unsigned m1 = (w1 == bmax) ? (unsigned)s1 : 0u;
        unsigned m2 = (w2 == bmax) ? (unsigned)s2 : 0u;
        unsigned m3 = (w3 == bmax) ? (unsigned)s3 : 0u;
        unsigned m4 = (w4 == bmax) ? (unsigned)s4 : 0u;
        unsigned m5 = (w5 == bmax) ? (unsigned)s5 : 0u;
        unsigned m6 = (w6 == bmax) ? (unsigned)s6 : 0u;
        unsigned m7 = (w7 == bmax) ? (unsigned)s7 : 0u;
        m0 = m0 > m1 ? m0 : m1;  m2 = m2 > m3 ? m2 : m3;
        m4 = m4 > m5 ? m4 : m5;  m6 = m6 > m7 ? m6 : m7;
        m0 = m0 > m2 ? m0 : m2;  m4 = m4 > m6 ? m4 : m6;
        const unsigned nsel = m0 > m4 ? m0 : m4;   // max ~idx == min idx (numpy tie rule)
        const int widx = (int)(~nsel);
        cx = xs[widx]; cy = ys[widx]; cz = zs[widx];   // broadcast LDS reads
        if (t == 0) {
            fps_idx[b*NP_ + it] = widx;
            size_t o3 = ((size_t)(b*NP_ + it)) * 3;
            new_xyzf[o3] = cx; new_xyzf[o3+1] = cy; new_xyzf[o3+2] = cz;
            out[o3] = cx; out[o3+1] = cy; out[o3+2] = cz;
        }
    }
}

// ---------------- ball query: one wave per center ----------------
__global__ __launch_bounds__(256) void ball_kernel(const float* __restrict__ xyz,
    const float* __restrict__ new_xyzf, int* __restrict__ ballidx)
{
#pragma clang fp contract(off)
    const int gw   = (blockIdx.x * 256 + threadIdx.x) >> 6;   // b*NP + p
    const int lane = threadIdx.x & 63;
    const int b    = gw >> 11;                                 // / NP_
    const float* X = xyz + (size_t)b * N_ * 3;
    const float cx = new_xyzf[(size_t)gw*3];
    const float cy = new_xyzf[(size_t)gw*3+1];
    const float cz = new_xyzf[(size_t)gw*3+2];
    int* outp = ballidx + (size_t)gw * NS_;
    int total = 0, first = -1;
    for (int base = 0; base < N_; base += 64) {
        const int j = base + lane;
        float dx = cx - X[j*3], dy = cy - X[j*3+1], dz = cz - X[j*3+2];
        float d2 = dx*dx;
        d2 = d2 + dy*dy;
        d2 = d2 + dz*dz;
        const bool in = d2 <= R2_;   // f64 threshold semantics of the reference
        ull m = __ballot(in);
        if (m) {
            if (first < 0) first = base + __builtin_ctzll(m);
            int r = total + __popcll(m & ((1ull << lane) - 1ull));
            if (in && r < NS_) outp[r] = j;
            total += (int)__popcll(m);
            if (total >= NS_) break;
        }
    }
    if (total < NS_) {
        int f = first < 0 ? 0 : first;
        if (lane >= total && lane < NS_) outp[lane] = f;
    }
}

// ---------------- layer1: fused gather + GEMM (67->64), store pre1 bf16 + stats ----------------
__global__ __launch_bounds__(256) void gemm1_kernel(const float* __restrict__ xyz,
    const __hip_bfloat16* __restrict__ featT, const float* __restrict__ newxyz,
    const int* __restrict__ ballidx, const float* __restrict__ W, const float* __restrict__ bias,
    __hip_bfloat16* __restrict__ pre1, float* __restrict__ psum, float* __restrict__ psumsq)
{
    const int lane = threadIdx.x & 63;
    const int gw   = (blockIdx.x * 256 + threadIdx.x) >> 6;   // 4096 waves
    float w[67];
#pragma unroll
    for (int k = 0; k < 67; ++k) w[k] = W[lane*67 + k];
    const float bs = bias[lane];
    float s1 = 0.f, s2 = 0.f;
    for (int r = gw; r < M_; r += 4096) {
        const int b = r >> 16;            // / (NP_*NS_)
        const int p = (r & 65535) >> 5;   // within-batch point
        const int j = ballidx[r];
        const float* xp = xyz    + ((size_t)b*N_  + j)*3;
        const float* cp = newxyz + ((size_t)b*NP_ + p)*3;
        float acc = bs;
        acc = fmaf(xp[0] - cp[0], w[0], acc);
        acc = fmaf(xp[1] - cp[1], w[1], acc);
        acc = fmaf(xp[2] - cp[2], w[2], acc);
        const unsigned* rp = (const unsigned*)(featT + ((size_t)b*N_ + j)*64);
#pragma unroll
        for (int kk = 0; kk < 32; ++kk) {
            unsigned u = rp[kk];
            float v0 = __uint_as_float(u << 16);
            float v1 = __uint_as_float(u & 0xffff0000u);
            acc = fmaf(v0, w[3 + 2*kk], acc);
            acc = fmaf(v1, w[4 + 2*kk], acc);
        }
        pre1[(size_t)r*64 + lane] = __float2bfloat16(acc);
        s1 += acc;
        s2 = fmaf(acc, acc, s2);
    }
    psum  [(size_t)gw*64 + lane] = s1;
    psumsq[(size_t)gw*64 + lane] = s2;
}

// ---------------- layer2: BN1+ReLU fused input, GEMM 64->64 IN PLACE + stats ----------------
__global__ __launch_bounds__(256) void gemm2_kernel(__hip_bfloat16* __restrict__ buf,
    const float* __restrict__ W, const float* __restrict__ bias,
    const float* __restrict__ bnsc, const float* __restrict__ bnsh,
    float* __restrict__ psum, float* __restrict__ psumsq)
{
    const int lane = threadIdx.x & 63;
    const int gw   = (blockIdx.x * 256 + threadIdx.x) >> 6;   // 4096 waves
    __shared__ float ssc[64], ssh[64];
    if (threadIdx.x < 64) { ssc[threadIdx.x] = bnsc[threadIdx.x]; ssh[threadIdx.x] = bnsh[threadIdx.x]; }
    __syncthreads();
    float w[64];
#pragma unroll
    for (int k = 0; k < 64; ++k) w[k] = W[lane*64 + k];
    const float bs = bias[lane];
    float s1 = 0.f, s2 = 0.f;
    for (int r = gw; r < M_; r += 4096) {
        const unsigned* rp = (const unsigned*)(buf + (size_t)r*64);
        float acc = bs;
#pragma unroll
        for (int kk = 0; kk < 32; ++kk) {
            unsigned u = rp[kk];
            float v0 = __uint_as_float(u << 16);
            float v1 = __uint_as_float(u & 0xffff0000u);
            v0 = fmaxf(fmaf(v0, ssc[2*kk],   ssh[2*kk]),   0.f);
            v1 = fmaxf(fmaf(v1, ssc[2*kk+1], ssh[2*kk+1]), 0.f);
            acc = fmaf(v0, w[2*kk],   acc);
            acc = fmaf(v1, w[2*kk+1], acc);
        }
        buf[(size_t)r*64 + lane] = __float2bfloat16(acc);   // in-place: row read fully above
        s1 += acc;
        s2 = fmaf(acc, acc, s2);
    }
    psum  [(size_t)gw*64 + lane] = s1;
    psumsq[(size_t)gw*64 + lane] = s2;
}

// ---------------- layer3: BN2+ReLU fused input, GEMM 64->128, fused per-point max/min ----------------
__global__ __launch_bounds__(256) void gemm3_kernel(const __hip_bfloat16* __restrict__ pre2,
    const float* __restrict__ W, const float* __restrict__ bias,
    const float* __restrict__ bnsc, const float* __restrict__ bnsh,
    float* __restrict__ mxb, float* __restrict__ mnb,
    float* __restrict__ psum, float* __restrict__ psumsq)
{
    const int lane = threadIdx.x & 63;
    const int gw   = (blockIdx.x * 256 + threadIdx.x) >> 6;   // 16384 waves
    const int pt   = gw >> 1;           // 8192 points
    const int half = gw & 1;
    __shared__ float ssc[64], ssh[64];
    if (threadIdx.x < 64) { ssc[threadIdx.x] = bnsc[threadIdx.x]; ssh[threadIdx.x] = bnsh[threadIdx.x]; }
    __syncthreads();
    const int o = half*64 + lane;
    float w[64];
#pragma unroll
    for (int k = 0; k < 64; ++k) w[k] = W[o*64 + k];
    const float bs = bias[o];
    float s1 = 0.f, s2 = 0.f, mx = -1e30f, mn = 1e30f;
    for (int s = 0; s < NS_; ++s) {
        const size_t r = (size_t)pt*NS_ + s;
        const unsigned* rp = (const unsigned*)(pre2 + r*64);
        float acc = bs;
#pragma unroll
        for (int kk = 0; kk < 32; ++kk) {
            unsigned u = rp[kk];
            float v0 = __uint_as_float(u << 16);
            float v1 = __uint_as_float(u & 0xffff0000u);
            v0 = fmaxf(fmaf(v0, ssc[2*kk],   ssh[2*kk]),   0.f);
            v1 = fmaxf(fmaf(v1, ssc[2*kk+1], ssh[2*kk+1]), 0.f);
            acc = fmaf(v0, w[2*kk],   acc);
            acc = fmaf(v1, w[2*kk+1], acc);
        }
        s1 += acc;
        s2 = fmaf(acc, acc, s2);
        mx = fmaxf(mx, acc);
        mn = fminf(mn, acc);
    }
    mxb[(size_t)pt*128 + o] = mx;
    mnb[(size_t)pt*128 + o] = mn;
    psum  [(size_t)pt*128 + o] = s1;
    psumsq[(size_t)pt*128 + o] = s2;
}

// ---------------- deterministic BN stat reduce -> scale/shift ----------------
template<int CO>
__global__ __launch_bounds__(256) void bnred_kernel(const float* __restrict__ psum,
    const float* __restrict__ psumsq, const float* __restrict__ g, const float* __restrict__ beta,
    float* __restrict__ sc, float* __restrict__ sh, int nslots)
{
    const int c = blockIdx.x;
    const int t = threadIdx.x;
    float s1 = 0, s2 = 0;
    for (int i = t; i < nslots; i += 256) {
        s1 += psum  [(size_t)i*CO + c];
        s2 += psumsq[(size_t)i*CO + c];
    }
    __shared__ float a1[256], a2[256];
    a1[t] = s1; a2[t] = s2;
    __syncthreads();
    for (int st = 128; st > 0; st >>= 1) {
        if (t < st) { a1[t] += a1[t+st]; a2[t] += a2[t+st]; }
        __syncthreads();
    }
    if (t == 0) {
        const float invM = 1.0f / (float)M_;
        float mu  = a1[0] * invM;
        float var = fmaxf(a2[0] * invM - mu*mu, 0.f);
        float rs  = 1.0f / sqrtf(var + EPS_);
        float s   = rs * g[c];
        sc[c] = s;
        sh[c] = fmaf(-mu, s, beta[c]);
    }
}

// ---------------- BN3 affine on max/min + ReLU, LDS transpose, write (B,128,NP) f32 ----------------
__global__ __launch_bounds__(256) void final_kernel(const float* __restrict__ mxb,
    const float* __restrict__ mnb, const float* __restrict__ sc, const float* __restrict__ sh,
    float* __restrict__ out)
{
    __shared__ float tile[128][65];
    const int b = blockIdx.y, p0 = blockIdx.x * 64;
    {
        const int o = threadIdx.x & 127, ph = threadIdx.x >> 7;
        const float s = sc[o], h = sh[o];
        const bool pos = (s >= 0.f);
        for (int pl = ph; pl < 64; pl += 2) {
            const size_t pt = (size_t)b*NP_ + p0 + pl;
            float v = pos ? mxb[pt*128 + o] : mnb[pt*128 + o];
            tile[o][pl] = fmaxf(fmaf(v, s, h), 0.f);   // max_s relu(affine) == relu(affine(max/min))
        }
    }
    __syncthreads();
    {
        const int p = threadIdx.x & 63, oh = threadIdx.x >> 6;
        for (int oo = oh; oo < 128; oo += 4)
            out[(size_t)(B_*NP_*3) + ((size_t)(b*128 + oo))*NP_ + p0 + p] = tile[oo][p];
    }
}

// ---------------- launch ----------------
extern "C" void kernel_launch(void* const* d_in, const int* in_sizes, int n_in,
                              void* d_out, int out_size, void* d_ws, size_t ws_size,
                              hipStream_t stream)
{
    const float* xyz  = (const float*)d_in[0];
    const float* feat = (const float*)d_in[1];
    const float* W0   = (const float*)d_in[2];
    const float* b0   = (const float*)d_in[3];
    const float* g0   = (const float*)d_in[4];
    const float* be0  = (const float*)d_in[5];
    const float* W1   = (const float*)d_in[6];
    const float* b1   = (const float*)d_in[7];
    const float* g1   = (const float*)d_in[8];
    const float* be1  = (const float*)d_in[9];
    const float* W2   = (const float*)d_in[10];
    const float* b2   = (const float*)d_in[11];
    const float* g2   = (const float*)d_in[12];
    const float* be2  = (const float*)d_in[13];

    char* ws = (char*)d_ws;                                  // total needed: ~53.1 MB
    int*   fpsidx = (int*)  (ws + 0);                        //  32 KB
    float* newxyz = (float*)(ws + 32768);                    //  96 KB
    int*   ball   = (int*)  (ws + 131072);                   //   1 MB
    float* scb    = (float*)(ws + 1179648);                  //   4 KB
    float* psum   = (float*)(ws + 1183744);                  //   4 MB
    float* psumsq = (float*)(ws + 5378048);                  //   4 MB
    __hip_bfloat16* featT = (__hip_bfloat16*)(ws + 9572352); //   4 MB
    float* mxb    = (float*)(ws + 13766656);                 //   4 MB
    float* mnb    = (float*)(ws + 17960960);                 //   4 MB
    __hip_bfloat16* buf1 = (__hip_bfloat16*)(ws + 22155264); //  32 MB (pre1, then pre2 in place)
    float* out = (float*)d_out;                              // reference outputs are float32

    float* sc1 = scb;       float* sh1 = scb + 128;
    float* sc2 = scb + 256; float* sh2 = scb + 384;
    float* sc3 = scb + 512; float* sh3 = scb + 640;

    transpose_kernel<<<dim3(N_/64, B_), 256, 0, stream>>>(feat, featT);
    fps_kernel<<<dim3(B_), 512, 0, stream>>>(xyz, fpsidx, newxyz, out);
    ball_kernel<<<dim3(B_*NP_/4), 256, 0, stream>>>(xyz, newxyz, ball);

    gemm1_kernel<<<1024, 256, 0, stream>>>(xyz, featT, newxyz, ball, W0, b0, buf1, psum, psumsq);
    bnred_kernel<64><<<64, 256, 0, stream>>>(psum, psumsq, g0, be0, sc1, sh1, 4096);
    gemm2_kernel<<<1024, 256, 0, stream>>>(buf1, W1, b1, sc1, sh1, psum, psumsq);
    bnred_kernel<64><<<64, 256, 0, stream>>>(psum, psumsq, g1, be1, sc2, sh2, 4096);
    gemm3_kernel<<<4096, 256, 0, stream>>>(buf1, W2, b2, sc2, sh2, mxb, mnb, psum, psumsq);
    bnred_kernel<128><<<128, 256, 0, stream>>>(psum, psumsq, g2, be2, sc3, sh3, 8192);
    final_kernel<<<dim3(NP_/64, B_), 256, 0, stream>>>(mxb, mnb, sc3, sh3, out);
}

// Round 10
// 2675.630 us; speedup vs baseline: 1.0429x; 1.0248x over previous
//
#include <hip/hip_runtime.h>
#include <hip/hip_bf16.h>
#include <cstdint>

#define B_   4
#define N_   8192
#define NP_  2048
#define NS_  32
#define CIN_ 64
#define M_   (B_*NP_*NS_)   // 262144 rows
#define EPS_ 1e-5f
#define R2_  0.01f          // d2 <= 0.01f  <=>  d2 < float64(0.1*0.1)

typedef unsigned long long ull;
typedef float v2f __attribute__((ext_vector_type(2)));

// ---------------- feature transpose: (B,CIN,N) f32 -> (B,N,CIN) bf16 ----------------
__global__ __launch_bounds__(256) void transpose_kernel(const float* __restrict__ feat,
                                                        __hip_bfloat16* __restrict__ featT)
{
    __shared__ float tile[64][65];
    const int b  = blockIdx.y;
    const int j0 = blockIdx.x * 64;
    const int tx = threadIdx.x & 63, ty = threadIdx.x >> 6;
    for (int cc = ty; cc < 64; cc += 4)
        tile[tx][cc] = feat[((size_t)(b*CIN_ + cc))*N_ + j0 + tx];
    __syncthreads();
    for (int cc = ty; cc < 64; cc += 4)
        featT[((size_t)(b*N_ + j0 + cc))*64 + tx] = __float2bfloat16(tile[cc][tx]);
}

// f32 max with DPP neighbor (invalid lanes keep old value -> identity under max)
template<int CTRL>
__device__ __forceinline__ float dppmaxf(float v)
{
    int o = __builtin_amdgcn_update_dpp(__float_as_int(v), __float_as_int(v), CTRL, 0xF, 0xF, false);
    return fmaxf(v, __int_as_float(o));
}

// ---- FPS: 1 block/batch, 256 thr x 32 pts (strided pairs), R7 scheme (DPP + atomicMax) ----
__global__ __launch_bounds__(256) void fps_kernel(const float* __restrict__ xyz,
    int* __restrict__ fps_idx, float* __restrict__ new_xyzf, float* __restrict__ out)
{
#pragma clang fp contract(off)
    const int b = blockIdx.x;
    const int t = threadIdx.x;
    const float* X = xyz + (size_t)b * N_ * 3;

    __shared__ float xs[N_], ys[N_], zs[N_];   // 96 KB SoA copy of this batch's xyz
    __shared__ float wavemax[4];
    __shared__ unsigned widx_slot[2];          // parity-buffered winner ~idx

    for (int p = t; p < N_; p += 256) {
        xs[p] = X[p*3+0]; ys[p] = X[p*3+1]; zs[p] = X[p*3+2];
    }
    if (t < 2) widx_slot[t] = 0u;

    // 32 points per thread, strided pairs (2g*256+t, (2g+1)*256+t)
    v2f px[16], py[16], pz[16], dst[16];
#pragma unroll
    for (int g = 0; g < 16; ++g) {
        const int p0 = (2*g)*256 + t, p1 = (2*g+1)*256 + t;
        px[g] = (v2f){X[p0*3+0], X[p1*3+0]};
        py[g] = (v2f){X[p0*3+1], X[p1*3+1]};
        pz[g] = (v2f){X[p0*3+2], X[p1*3+2]};
        dst[g] = (v2f){1e10f, 1e10f};
    }
    const int wv = t >> 6, ln = t & 63;

    float cx = X[0], cy = X[1], cz = X[2];   // first sampled point = index 0
    if (t == 0) {
        fps_idx[b*NP_] = 0;
        size_t o3 = (size_t)(b*NP_) * 3;
        new_xyzf[o3] = cx; new_xyzf[o3+1] = cy; new_xyzf[o3+2] = cz;
        out[o3] = cx; out[o3+1] = cy; out[o3+2] = cz;
    }
    for (int it = 1; it < NP_; ++it) {
        const int par = it & 1;
        // phase 1: packed distance update + per-thread best VALUE
        v2f bm = (v2f){-1.0f, -1.0f};
        const v2f c0 = (v2f){cx, cx}, c1 = (v2f){cy, cy}, c2 = (v2f){cz, cz};
#pragma unroll
        for (int g = 0; g < 16; ++g) {
            v2f dx = px[g] - c0, dy = py[g] - c1, dz = pz[g] - c2;
            v2f dd = dx*dx;          // contract(off): exact numpy op order per component
            dd = dd + dy*dy;
            dd = dd + dz*dz;
            v2f nd;
            nd.x = fminf(dst[g].x, dd.x);
            nd.y = fminf(dst[g].y, dd.y);
            dst[g] = nd;
            bm.x = fmaxf(bm.x, nd.x);
            bm.y = fmaxf(bm.y, nd.y);
        }
        const float bestv = fmaxf(bm.x, bm.y);
        // phase 2: wave max via DPP -> LDS slot per wave
        float wm = bestv;
        wm = dppmaxf<0x111>(wm);
        wm = dppmaxf<0x112>(wm);
        wm = dppmaxf<0x114>(wm);
        wm = dppmaxf<0x118>(wm);
        wm = dppmaxf<0x142>(wm);
        wm = dppmaxf<0x143>(wm);
        if (ln == 63) wavemax[wv] = wm;
        __syncthreads();                       // barrier A
        if (t == 0) widx_slot[par ^ 1] = 0u;   // reset other-parity slot (barrier-ordered)
        const float bmax = fmaxf(fmaxf(wavemax[0], wavemax[1]), fmaxf(wavemax[2], wavemax[3]));
        // index recovery: only winning thread(s) rescan registers (exec-masked branch)
        if (bestv == bmax) {
            unsigned nin = 0u;
#pragma unroll
            for (int g = 15; g >= 0; --g) {    // descending: last assignment = smallest index
                if (dst[g].y == bmax) nin = ~(unsigned)((2*g+1)*256 + t);
                if (dst[g].x == bmax) nin = ~(unsigned)((2*g)*256 + t);
            }
            atomicMax(&widx_slot[par], nin);   // max ~idx == min idx (numpy tie rule)
        }
        __syncthreads();                       // barrier B
        const int widx = (int)(~widx_slot[par]);
        cx = xs[widx]; cy = ys[widx]; cz = zs[widx];   // broadcast LDS reads
        if (t == 0) {
            fps_idx[b*NP_ + it] = widx;
            size_t o3 = ((size_t)(b*NP_ + it)) * 3;
            new_xyzf[o3] = cx; new_xyzf[o3+1] = cy; new_xyzf[o3+2] = cz;
            out[o3] = cx; out[o3+1] = cy; out[o3+2] = cz;
        }
    }
}

// ---------------- ball query: one wave per center ----------------
__global__ __launch_bounds__(256) void ball_kernel(const float* __restrict__ xyz,
    const float* __restrict__ new_xyzf, int* __restrict__ ballidx)
{
#pragma clang fp contract(off)
    const int gw   = (blockIdx.x * 256 + threadIdx.x) >> 6;   // b*NP + p
    const int lane = threadIdx.x & 63;
    const int b    = gw >> 11;                                 // / NP_
    const float* X = xyz + (size_t)b * N_ * 3;
    const float cx = new_xyzf[(size_t)gw*3];
    const float cy = new_xyzf[(size_t)gw*3+1];
    const float cz = new_xyzf[(size_t)gw*3+2];
    int* outp = ballidx + (size_t)gw * NS_;
    int total = 0, first = -1;
    for (int base = 0; base < N_; base += 64) {
        const int j = base + lane;
        float dx = cx - X[j*3], dy = cy - X[j*3+1], dz = cz - X[j*3+2];
        float d2 = dx*dx;
        d2 = d2 + dy*dy;
        d2 = d2 + dz*dz;
        const bool in = d2 <= R2_;   // f64 threshold semantics of the reference
        ull m = __ballot(in);
        if (m) {
            if (first < 0) first = base + __builtin_ctzll(m);
            int r = total + __popcll(m & ((1ull << lane) - 1ull));
            if (in && r < NS_) outp[r] = j;
            total += (int)__popcll(m);
            if (total >= NS_) break;
        }
    }
    if (total < NS_) {
        int f = first < 0 ? 0 : first;
        if (lane >= total && lane < NS_) outp[lane] = f;
    }
}

// ---------------- layer1: fused gather + GEMM (67->64), uint4 row loads ----------------
__global__ __launch_bounds__(256) void gemm1_kernel(const float* __restrict__ xyz,
    const __hip_bfloat16* __restrict__ featT, const float* __restrict__ newxyz,
    const int* __restrict__ ballidx, const float* __restrict__ W, const float* __restrict__ bias,
    __hip_bfloat16* __restrict__ pre1, float* __restrict__ psum, float* __restrict__ psumsq)
{
    const int lane = threadIdx.x & 63;
    const int gw   = (blockIdx.x * 256 + threadIdx.x) >> 6;   // 4096 waves
    float w[67];
#pragma unroll
    for (int k = 0; k < 67; ++k) w[k] = W[lane*67 + k];
    const float bs = bias[lane];
    float s1 = 0.f, s2 = 0.f;
    for (int r = gw; r < M_; r += 4096) {
        const int b = r >> 16;            // / (NP_*NS_)
        const int p = (r & 65535) >> 5;   // within-batch point
        const int j = ballidx[r];
        const float* xp = xyz    + ((size_t)b*N_  + j)*3;
        const float* cp = newxyz + ((size_t)b*NP_ + p)*3;
        float acc = bs;
        acc = fmaf(xp[0] - cp[0], w[0], acc);
        acc = fmaf(xp[1] - cp[1], w[1], acc);
        acc = fmaf(xp[2] - cp[2], w[2], acc);
        const uint4* rp = (const uint4*)(featT + ((size_t)b*N_ + j)*64);
#pragma unroll
        for (int q = 0; q < 8; ++q) {
            const uint4 u4 = rp[q];
            const unsigned uu0 = u4.x, uu1 = u4.y, uu2 = u4.z, uu3 = u4.w;
            acc = fmaf(__uint_as_float(uu0 << 16),         w[3 + q*8 + 0], acc);
            acc = fmaf(__uint_as_float(uu0 & 0xffff0000u), w[3 + q*8 + 1], acc);
            acc = fmaf(__uint_as_float(uu1 << 16),         w[3 + q*8 + 2], acc);
            acc = fmaf(__uint_as_float(uu1 & 0xffff0000u), w[3 + q*8 + 3], acc);
            acc = fmaf(__uint_as_float(uu2 << 16),         w[3 + q*8 + 4], acc);
            acc = fmaf(__uint_as_float(uu2 & 0xffff0000u), w[3 + q*8 + 5], acc);
            acc = fmaf(__uint_as_float(uu3 << 16),         w[3 + q*8 + 6], acc);
            acc = fmaf(__uint_as_float(uu3 & 0xffff0000u), w[3 + q*8 + 7], acc);
        }
        pre1[(size_t)r*64 + lane] = __float2bfloat16(acc);
        s1 += acc;
        s2 = fmaf(acc, acc, s2);
    }
    psum  [(size_t)gw*64 + lane] = s1;
    psumsq[(size_t)gw*64 + lane] = s2;
}

// ---------------- layer2: BN1+ReLU fused input, GEMM 64->64 IN PLACE, uint4 loads ----------------
__global__ __launch_bounds__(256) void gemm2_kernel(__hip_bfloat16* __restrict__ buf,
    const float* __restrict__ W, const float* __restrict__ bias,
    const float* __restrict__ bnsc, const float* __restrict__ bnsh,
    float* __restrict__ psum, float* __restrict__ psumsq)
{
    const int lane = threadIdx.x & 63;
    const int gw   = (blockIdx.x * 256 + threadIdx.x) >> 6;   // 4096 waves
    __shared__ float ssc[64], ssh[64];
    if (threadIdx.x < 64) { ssc[threadIdx.x] = bnsc[threadIdx.x]; ssh[threadIdx.x] = bnsh[threadIdx.x]; }
    __syncthreads();
    float w[64];
#pragma unroll
    for (int k = 0; k < 64; ++k) w[k] = W[lane*64 + k];
    const float bs = bias[lane];
    float s1 = 0.f, s2 = 0.f;
    for (int r = gw; r < M_; r += 4096) {
        const uint4* rp = (const uint4*)(buf + (size_t)r*64);
        float acc = bs;
#pragma unroll
        for (int q = 0; q < 8; ++q) {
            const uint4 u4 = rp[q];
            const unsigned uu[4] = {u4.x, u4.y, u4.z, u4.w};
#pragma unroll
            for (int m = 0; m < 4; ++m) {
                const int k = q*8 + m*2;
                float v0 = __uint_as_float(uu[m] << 16);
                float v1 = __uint_as_float(uu[m] & 0xffff0000u);
                v0 = fmaxf(fmaf(v0, ssc[k],   ssh[k]),   0.f);
                v1 = fmaxf(fmaf(v1, ssc[k+1], ssh[k+1]), 0.f);
                acc = fmaf(v0, w[k],   acc);
                acc = fmaf(v1, w[k+1], acc);
            }
        }
        buf[(size_t)r*64 + lane] = __float2bfloat16(acc);   // in-place: row read fully above
        s1 += acc;
        s2 = fmaf(acc, acc, s2);
    }
    psum  [(size_t)gw*64 + lane] = s1;
    psumsq[(size_t)gw*64 + lane] = s2;
}

// ---------------- layer3: BN2+ReLU fused input, GEMM 64->128, uint4 loads, max/min ----------------
__global__ __launch_bounds__(256) void gemm3_kernel(const __hip_bfloat16* __restrict__ pre2,
    const float* __restrict__ W, const float* __restrict__ bias,
    const float* __restrict__ bnsc, const float* __restrict__ bnsh,
    float* __restrict__ mxb, float* __restrict__ mnb,
    float* __restrict__ psum, float* __restrict__ psumsq)
{
    const int lane = threadIdx.x & 63;
    const int gw   = (blockIdx.x * 256 + threadIdx.x) >> 6;   // 16384 waves
    const int pt   = gw >> 1;           // 8192 points
    const int half = gw & 1;
    __shared__ float ssc[64], ssh[64];
    if (threadIdx.x < 64) { ssc[threadIdx.x] = bnsc[threadIdx.x]; ssh[threadIdx.x] = bnsh[threadIdx.x]; }
    __syncthreads();
    const int o = half*64 + lane;
    float w[64];
#pragma unroll
    for (int k = 0; k < 64; ++k) w[k] = W[o*64 + k];
    const float bs = bias[o];
    float s1 = 0.f, s2 = 0.f, mx = -1e30f, mn = 1e30f;
    for (int s = 0; s < NS_; ++s) {
        const size_t r = (size_t)pt*NS_ + s;
        const uint4* rp = (const uint4*)(pre2 + r*64);
        float acc = bs;
#pragma unroll
        for (int q = 0; q < 8; ++q) {
            const uint4 u4 = rp[q];
            const unsigned uu[4] = {u4.x, u4.y, u4.z, u4.w};
#pragma unroll
            for (int m = 0; m < 4; ++m) {
                const int k = q*8 + m*2;
                float v0 = __uint_as_float(uu[m] << 16);
                float v1 = __uint_as_float(uu[m] & 0xffff0000u);
                v0 = fmaxf(fmaf(v0, ssc[k],   ssh[k]),   0.f);
                v1 = fmaxf(fmaf(v1, ssc[k+1], ssh[k+1]), 0.f);
                acc = fmaf(v0, w[k],   acc);
                acc = fmaf(v1, w[k+1], acc);
            }
        }
        s1 += acc;
        s2 = fmaf(acc, acc, s2);
        mx = fmaxf(mx, acc);
        mn = fminf(mn, acc);
    }
    mxb[(size_t)pt*128 + o] = mx;
    mnb[(size_t)pt*128 + o] = mn;
    psum  [(size_t)pt*128 + o] = s1;
    psumsq[(size_t)pt*128 + o] = s2;
}

// ---------------- deterministic BN stat reduce -> scale/shift ----------------
template<int CO>
__global__ __launch_bounds__(256) void bnred_kernel(const float* __restrict__ psum,
    const float* __restrict__ psumsq, const float* __restrict__ g, const float* __restrict__ beta,
    float* __restrict__ sc, float* __restrict__ sh, int nslots)
{
    const int c = blockIdx.x;
    const int t = threadIdx.x;
    float s1 = 0, s2 = 0;
    for (int i = t; i < nslots; i += 256) {
        s1 += psum  [(size_t)i*CO + c];
        s2 += psumsq[(size_t)i*CO + c];
    }
    __shared__ float a1[256], a2[256];
    a1[t] = s1; a2[t] = s2;
    __syncthreads();
    for (int st = 128; st > 0; st >>= 1) {
        if (t < st) { a1[t] += a1[t+st]; a2[t] += a2[t+st]; }
        __syncthreads();
    }
    if (t == 0) {
        const float invM = 1.0f / (float)M_;
        float mu  = a1[0] * invM;
        float var = fmaxf(a2[0] * invM - mu*mu, 0.f);
        float rs  = 1.0f / sqrtf(var + EPS_);
        float s   = rs * g[c];
        sc[c] = s;
        sh[c] = fmaf(-mu, s, beta[c]);
    }
}

// ---------------- BN3 affine on max/min + ReLU, LDS transpose, write (B,128,NP) f32 ----------------
__global__ __launch_bounds__(256) void final_kernel(const float* __restrict__ mxb,
    const float* __restrict__ mnb, const float* __restrict__ sc, const float* __restrict__ sh,
    float* __restrict__ out)
{
    __shared__ float tile[128][65];
    const int b = blockIdx.y, p0 = blockIdx.x * 64;
    {
        const int o = threadIdx.x & 127, ph = threadIdx.x >> 7;
        const float s = sc[o], h = sh[o];
        const bool pos = (s >= 0.f);
        for (int pl = ph; pl < 64; pl += 2) {
            const size_t pt = (size_t)b*NP_ + p0 + pl;
            float v = pos ? mxb[pt*128 + o] : mnb[pt*128 + o];
            tile[o][pl] = fmaxf(fmaf(v, s, h), 0.f);   // max_s relu(affine) == relu(affine(max/min))
        }
    }
    __syncthreads();
    {
        const int p = threadIdx.x & 63, oh = threadIdx.x >> 6;
        for (int oo = oh; oo < 128; oo += 4)
            out[(size_t)(B_*NP_*3) + ((size_t)(b*128 + oo))*NP_ + p0 + p] = tile[oo][p];
    }
}

// ---------------- launch ----------------
extern "C" void kernel_launch(void* const* d_in, const int* in_sizes, int n_in,
                              void* d_out, int out_size, void* d_ws, size_t ws_size,
                              hipStream_t stream)
{
    const float* xyz  = (const float*)d_in[0];
    const float* feat = (const float*)d_in[1];
    const float* W0   = (const float*)d_in[2];
    const float* b0   = (const float*)d_in[3];
    const float* g0   = (const float*)d_in[4];
    const float* be0  = (const float*)d_in[5];
    const float* W1   = (const float*)d_in[6];
    const float* b1   = (const float*)d_in[7];
    const float* g1   = (const float*)d_in[8];
    const float* be1  = (const float*)d_in[9];
    const float* W2   = (const float*)d_in[10];
    const float* b2   = (const float*)d_in[11];
    const float* g2   = (const float*)d_in[12];
    const float* be2  = (const float*)d_in[13];

    char* ws = (char*)d_ws;                                  // total needed: ~53.1 MB
    int*   fpsidx = (int*)  (ws + 0);                        //  32 KB
    float* newxyz = (float*)(ws + 32768);                    //  96 KB
    int*   ball   = (int*)  (ws + 131072);                   //   1 MB
    float* scb    = (float*)(ws + 1179648);                  //   4 KB
    float* psum   = (float*)(ws + 1183744);                  //   4 MB
    float* psumsq = (float*)(ws + 5378048);                  //   4 MB
    __hip_bfloat16* featT = (__hip_bfloat16*)(ws + 9572352); //   4 MB
    float* mxb    = (float*)(ws + 13766656);                 //   4 MB
    float* mnb    = (float*)(ws + 17960960);                 //   4 MB
    __hip_bfloat16* buf1 = (__hip_bfloat16*)(ws + 22155264); //  32 MB (pre1, then pre2 in place)
    float* out = (float*)d_out;                              // reference outputs are float32

    float* sc1 = scb;       float* sh1 = scb + 128;
    float* sc2 = scb + 256; float* sh2 = scb + 384;
    float* sc3 = scb + 512; float* sh3 = scb + 640;

    transpose_kernel<<<dim3(N_/64, B_), 256, 0, stream>>>(feat, featT);
    fps_kernel<<<dim3(B_), 256, 0, stream>>>(xyz, fpsidx, newxyz, out);
    ball_kernel<<<dim3(B_*NP_/4), 256, 0, stream>>>(xyz, newxyz, ball);

    gemm1_kernel<<<1024, 256, 0, stream>>>(xyz, featT, newxyz, ball, W0, b0, buf1, psum, psumsq);
    bnred_kernel<64><<<64, 256, 0, stream>>>(psum, psumsq, g0, be0, sc1, sh1, 4096);
    gemm2_kernel<<<1024, 256, 0, stream>>>(buf1, W1, b1, sc1, sh1, psum, psumsq);
    bnred_kernel<64><<<64, 256, 0, stream>>>(psum, psumsq, g1, be1, sc2, sh2, 4096);
    gemm3_kernel<<<4096, 256, 0, stream>>>(buf1, W2, b2, sc2, sh2, mxb, mnb, psum, psumsq);
    bnred_kernel<128><<<128, 256, 0, stream>>>(psum, psumsq, g2, be2, sc3, sh3, 8192);
    final_kernel<<<dim3(NP_/64, B_), 256, 0, stream>>>(mxb, mnb, sc3, sh3, out);
}

// Round 11
// 2381.025 us; speedup vs baseline: 1.1719x; 1.1237x over previous
//
#include <hip/hip_runtime.h>
#include <hip/hip_bf16.h>
#include <cstdint>

#define B_   4
#define N_   8192
#define NP_  2048
#define NS_  32
#define CIN_ 64
#define M_   (B_*NP_*NS_)   // 262144 rows
#define EPS_ 1e-5f
#define R2_  0.01f          // d2 <= 0.01f  <=>  d2 < float64(0.1*0.1)

typedef unsigned long long ull;
typedef float v2f __attribute__((ext_vector_type(2)));

// ---------------- feature transpose: (B,CIN,N) f32 -> (B,N,CIN) bf16 ----------------
__global__ __launch_bounds__(256) void transpose_kernel(const float* __restrict__ feat,
                                                        __hip_bfloat16* __restrict__ featT)
{
    __shared__ float tile[64][65];
    const int b  = blockIdx.y;
    const int j0 = blockIdx.x * 64;
    const int tx = threadIdx.x & 63, ty = threadIdx.x >> 6;
    for (int cc = ty; cc < 64; cc += 4)
        tile[tx][cc] = feat[((size_t)(b*CIN_ + cc))*N_ + j0 + tx];
    __syncthreads();
    for (int cc = ty; cc < 64; cc += 4)
        featT[((size_t)(b*N_ + j0 + cc))*64 + tx] = __float2bfloat16(tile[cc][tx]);
}

// f32 max with DPP neighbor (invalid lanes keep old value -> identity under max)
template<int CTRL>
__device__ __forceinline__ float dppmaxf(float v)
{
    int o = __builtin_amdgcn_update_dpp(__float_as_int(v), __float_as_int(v), CTRL, 0xF, 0xF, false);
    return fmaxf(v, __int_as_float(o));
}

// ---- FPS (R7 verbatim, measured best 1903us): 512 thr x 16 pts, DPP value-max + atomicMax ----
__global__ __launch_bounds__(512) void fps_kernel(const float* __restrict__ xyz,
    int* __restrict__ fps_idx, float* __restrict__ new_xyzf, float* __restrict__ out)
{
#pragma clang fp contract(off)
    const int b = blockIdx.x;
    const int t = threadIdx.x;
    const float* X = xyz + (size_t)b * N_ * 3;

    __shared__ float xs[N_], ys[N_], zs[N_];   // 96 KB SoA copy of this batch's xyz
    __shared__ float wavemax[8];
    __shared__ unsigned widx_slot[2];          // parity-buffered winner ~idx

    for (int p = t; p < N_; p += 512) {
        xs[p] = X[p*3+0]; ys[p] = X[p*3+1]; zs[p] = X[p*3+2];
    }
    if (t < 2) widx_slot[t] = 0u;

    // 16 points per thread, strided; pairs (2g*512+t, (2g+1)*512+t)
    v2f px[8], py[8], pz[8], dst[8];
#pragma unroll
    for (int g = 0; g < 8; ++g) {
        const int p0 = (2*g)*512 + t, p1 = (2*g+1)*512 + t;
        px[g] = (v2f){X[p0*3+0], X[p1*3+0]};
        py[g] = (v2f){X[p0*3+1], X[p1*3+1]};
        pz[g] = (v2f){X[p0*3+2], X[p1*3+2]};
        dst[g] = (v2f){1e10f, 1e10f};
    }
    const int wv = t >> 6, ln = t & 63;

    float cx = X[0], cy = X[1], cz = X[2];   // first sampled point = index 0
    if (t == 0) {
        fps_idx[b*NP_] = 0;
        size_t o3 = (size_t)(b*NP_) * 3;
        new_xyzf[o3] = cx; new_xyzf[o3+1] = cy; new_xyzf[o3+2] = cz;
        out[o3] = cx; out[o3+1] = cy; out[o3+2] = cz;
    }
    for (int it = 1; it < NP_; ++it) {
        const int par = it & 1;
        // phase 1: distance update + per-thread best VALUE only
        float bestv = -1.0f;
        const v2f c0 = (v2f){cx, cx}, c1 = (v2f){cy, cy}, c2 = (v2f){cz, cz};
#pragma unroll
        for (int g = 0; g < 8; ++g) {
            v2f dx = px[g] - c0, dy = py[g] - c1, dz = pz[g] - c2;
            v2f dd = dx*dx;          // contract(off): exact numpy op order per component
            dd = dd + dy*dy;
            dd = dd + dz*dz;
            v2f nd;
            nd.x = fminf(dst[g].x, dd.x);
            nd.y = fminf(dst[g].y, dd.y);
            dst[g] = nd;
            bestv = fmaxf(bestv, nd.x);
            bestv = fmaxf(bestv, nd.y);
        }
        // phase 2: wave max via DPP -> LDS slot per wave
        float wm = bestv;
        wm = dppmaxf<0x111>(wm);
        wm = dppmaxf<0x112>(wm);
        wm = dppmaxf<0x114>(wm);
        wm = dppmaxf<0x118>(wm);
        wm = dppmaxf<0x142>(wm);
        wm = dppmaxf<0x143>(wm);
        if (ln == 63) wavemax[wv] = wm;
        __syncthreads();                       // barrier A
        if (t == 0) widx_slot[par ^ 1] = 0u;   // reset other-parity slot (barrier-ordered)
        float bmax = fmaxf(fmaxf(fmaxf(wavemax[0], wavemax[1]), fmaxf(wavemax[2], wavemax[3])),
                           fmaxf(fmaxf(wavemax[4], wavemax[5]), fmaxf(wavemax[6], wavemax[7])));
        // index recovery: only winning thread(s) rescan registers (exec-masked branch)
        if (bestv == bmax) {
            unsigned nin = 0u;
#pragma unroll
            for (int g = 7; g >= 0; --g) {     // descending: last assignment = smallest index
                if (dst[g].y == bmax) nin = ~(unsigned)((2*g+1)*512 + t);
                if (dst[g].x == bmax) nin = ~(unsigned)((2*g)*512 + t);
            }
            atomicMax(&widx_slot[par], nin);   // max ~idx == min idx (numpy tie rule)
        }
        __syncthreads();                       // barrier B
        const int widx = (int)(~widx_slot[par]);
        cx = xs[widx]; cy = ys[widx]; cz = zs[widx];   // broadcast LDS reads
        if (t == 0) {
            fps_idx[b*NP_ + it] = widx;
            size_t o3 = ((size_t)(b*NP_ + it)) * 3;
            new_xyzf[o3] = cx; new_xyzf[o3+1] = cy; new_xyzf[o3+2] = cz;
            out[o3] = cx; out[o3+1] = cy; out[o3+2] = cz;
        }
    }
}

// ---------------- ball query: one wave per center ----------------
__global__ __launch_bounds__(256) void ball_kernel(const float* __restrict__ xyz,
    const float* __restrict__ new_xyzf, int* __restrict__ ballidx)
{
#pragma clang fp contract(off)
    const int gw   = (blockIdx.x * 256 + threadIdx.x) >> 6;   // b*NP + p
    const int lane = threadIdx.x & 63;
    const int b    = gw >> 11;                                 // / NP_
    const float* X = xyz + (size_t)b * N_ * 3;
    const float cx = new_xyzf[(size_t)gw*3];
    const float cy = new_xyzf[(size_t)gw*3+1];
    const float cz = new_xyzf[(size_t)gw*3+2];
    int* outp = ballidx + (size_t)gw * NS_;
    int total = 0, first = -1;
    for (int base = 0; base < N_; base += 64) {
        const int j = base + lane;
        float dx = cx - X[j*3], dy = cy - X[j*3+1], dz = cz - X[j*3+2];
        float d2 = dx*dx;
        d2 = d2 + dy*dy;
        d2 = d2 + dz*dz;
        const bool in = d2 <= R2_;   // f64 threshold semantics of the reference
        ull m = __ballot(in);
        if (m) {
            if (first < 0) first = base + __builtin_ctzll(m);
            int r = total + __popcll(m & ((1ull << lane) - 1ull));
            if (in && r < NS_) outp[r] = j;
            total += (int)__popcll(m);
            if (total >= NS_) break;
        }
    }
    if (total < NS_) {
        int f = first < 0 ? 0 : first;
        if (lane >= total && lane < NS_) outp[lane] = f;
    }
}

// ---------------- layer1: fused gather + GEMM (67->64), uint4 row loads ----------------
__global__ __launch_bounds__(256) void gemm1_kernel(const float* __restrict__ xyz,
    const __hip_bfloat16* __restrict__ featT, const float* __restrict__ newxyz,
    const int* __restrict__ ballidx, const float* __restrict__ W, const float* __restrict__ bias,
    __hip_bfloat16* __restrict__ pre1, float* __restrict__ psum, float* __restrict__ psumsq)
{
    const int lane = threadIdx.x & 63;
    const int gw   = (blockIdx.x * 256 + threadIdx.x) >> 6;   // 4096 waves
    float w[67];
#pragma unroll
    for (int k = 0; k < 67; ++k) w[k] = W[lane*67 + k];
    const float bs = bias[lane];
    float s1 = 0.f, s2 = 0.f;
    for (int r = gw; r < M_; r += 4096) {
        const int b = r >> 16;            // / (NP_*NS_)
        const int p = (r & 65535) >> 5;   // within-batch point
        const int j = ballidx[r];
        const float* xp = xyz    + ((size_t)b*N_  + j)*3;
        const float* cp = newxyz + ((size_t)b*NP_ + p)*3;
        float acc = bs;
        acc = fmaf(xp[0] - cp[0], w[0], acc);
        acc = fmaf(xp[1] - cp[1], w[1], acc);
        acc = fmaf(xp[2] - cp[2], w[2], acc);
        const uint4* rp = (const uint4*)(featT + ((size_t)b*N_ + j)*64);
#pragma unroll
        for (int q = 0; q < 8; ++q) {
            const uint4 u4 = rp[q];
            const unsigned uu0 = u4.x, uu1 = u4.y, uu2 = u4.z, uu3 = u4.w;
            acc = fmaf(__uint_as_float(uu0 << 16),         w[3 + q*8 + 0], acc);
            acc = fmaf(__uint_as_float(uu0 & 0xffff0000u), w[3 + q*8 + 1], acc);
            acc = fmaf(__uint_as_float(uu1 << 16),         w[3 + q*8 + 2], acc);
            acc = fmaf(__uint_as_float(uu1 & 0xffff0000u), w[3 + q*8 + 3], acc);
            acc = fmaf(__uint_as_float(uu2 << 16),         w[3 + q*8 + 4], acc);
            acc = fmaf(__uint_as_float(uu2 & 0xffff0000u), w[3 + q*8 + 5], acc);
            acc = fmaf(__uint_as_float(uu3 << 16),         w[3 + q*8 + 6], acc);
            acc = fmaf(__uint_as_float(uu3 & 0xffff0000u), w[3 + q*8 + 7], acc);
        }
        pre1[(size_t)r*64 + lane] = __float2bfloat16(acc);
        s1 += acc;
        s2 = fmaf(acc, acc, s2);
    }
    psum  [(size_t)gw*64 + lane] = s1;
    psumsq[(size_t)gw*64 + lane] = s2;
}

// ---------------- elementwise BN+ReLU in place on bf16 buffer (one uint4 = 8 elems/thr) ----------
__global__ __launch_bounds__(256) void epi_kernel(__hip_bfloat16* __restrict__ buf,
    const float* __restrict__ sc, const float* __restrict__ sh)
{
    __shared__ float ssc[64], ssh[64];
    if (threadIdx.x < 64) { ssc[threadIdx.x] = sc[threadIdx.x]; ssh[threadIdx.x] = sh[threadIdx.x]; }
    __syncthreads();
    const size_t idx = (size_t)blockIdx.x * 256 + threadIdx.x;   // uint4 index; 8 elems
    const int k0 = (threadIdx.x & 7) * 8;                        // k offset within the 64-ch row
    uint4* p = (uint4*)buf;
    uint4 u = p[idx];
    unsigned wds[4] = {u.x, u.y, u.z, u.w};
    unsigned res[4];
#pragma unroll
    for (int m = 0; m < 4; ++m) {
        const int k = k0 + m*2;
        float v0 = __uint_as_float(wds[m] << 16);
        float v1 = __uint_as_float(wds[m] & 0xffff0000u);
        v0 = fmaxf(fmaf(v0, ssc[k],   ssh[k]),   0.f);
        v1 = fmaxf(fmaf(v1, ssc[k+1], ssh[k+1]), 0.f);
        __hip_bfloat16 b0 = __float2bfloat16(v0);
        __hip_bfloat16 b1 = __float2bfloat16(v1);
        unsigned short s0 = *reinterpret_cast<unsigned short*>(&b0);
        unsigned short s1 = *reinterpret_cast<unsigned short*>(&b1);
        res[m] = (unsigned)s0 | ((unsigned)s1 << 16);
    }
    p[idx] = make_uint4(res[0], res[1], res[2], res[3]);
}

// ---------------- layer2: GEMM 64->64 IN PLACE (input already BN+ReLU'd), uint4 loads ----------
__global__ __launch_bounds__(256) void gemm2_kernel(__hip_bfloat16* __restrict__ buf,
    const float* __restrict__ W, const float* __restrict__ bias,
    float* __restrict__ psum, float* __restrict__ psumsq)
{
    const int lane = threadIdx.x & 63;
    const int gw   = (blockIdx.x * 256 + threadIdx.x) >> 6;   // 4096 waves
    float w[64];
#pragma unroll
    for (int k = 0; k < 64; ++k) w[k] = W[lane*64 + k];
    const float bs = bias[lane];
    float s1 = 0.f, s2 = 0.f;
    for (int r = gw; r < M_; r += 4096) {
        const uint4* rp = (const uint4*)(buf + (size_t)r*64);
        float acc = bs;
#pragma unroll
        for (int q = 0; q < 8; ++q) {
            const uint4 u4 = rp[q];
            const unsigned uu0 = u4.x, uu1 = u4.y, uu2 = u4.z, uu3 = u4.w;
            acc = fmaf(__uint_as_float(uu0 << 16),         w[q*8 + 0], acc);
            acc = fmaf(__uint_as_float(uu0 & 0xffff0000u), w[q*8 + 1], acc);
            acc = fmaf(__uint_as_float(uu1 << 16),         w[q*8 + 2], acc);
            acc = fmaf(__uint_as_float(uu1 & 0xffff0000u), w[q*8 + 3], acc);
            acc = fmaf(__uint_as_float(uu2 << 16),         w[q*8 + 4], acc);
            acc = fmaf(__uint_as_float(uu2 & 0xffff0000u), w[q*8 + 5], acc);
            acc = fmaf(__uint_as_float(uu3 << 16),         w[q*8 + 6], acc);
            acc = fmaf(__uint_as_float(uu3 & 0xffff0000u), w[q*8 + 7], acc);
        }
        buf[(size_t)r*64 + lane] = __float2bfloat16(acc);   // in-place: row read fully above
        s1 += acc;
        s2 = fmaf(acc, acc, s2);
    }
    psum  [(size_t)gw*64 + lane] = s1;
    psumsq[(size_t)gw*64 + lane] = s2;
}

// ---------------- layer3: GEMM 64->128 (input already BN+ReLU'd), max/min fused ----------------
__global__ __launch_bounds__(256) void gemm3_kernel(const __hip_bfloat16* __restrict__ act2,
    const float* __restrict__ W, const float* __restrict__ bias,
    float* __restrict__ mxb, float* __restrict__ mnb,
    float* __restrict__ psum, float* __restrict__ psumsq)
{
    const int lane = threadIdx.x & 63;
    const int gw   = (blockIdx.x * 256 + threadIdx.x) >> 6;   // 16384 waves
    const int pt   = gw >> 1;           // 8192 points
    const int half = gw & 1;
    const int o = half*64 + lane;
    float w[64];
#pragma unroll
    for (int k = 0; k < 64; ++k) w[k] = W[o*64 + k];
    const float bs = bias[o];
    float s1 = 0.f, s2 = 0.f, mx = -1e30f, mn = 1e30f;
    for (int s = 0; s < NS_; ++s) {
        const size_t r = (size_t)pt*NS_ + s;
        const uint4* rp = (const uint4*)(act2 + r*64);
        float acc = bs;
#pragma unroll
        for (int q = 0; q < 8; ++q) {
            const uint4 u4 = rp[q];
            const unsigned uu0 = u4.x, uu1 = u4.y, uu2 = u4.z, uu3 = u4.w;
            acc = fmaf(__uint_as_float(uu0 << 16),         w[q*8 + 0], acc);
            acc = fmaf(__uint_as_float(uu0 & 0xffff0000u), w[q*8 + 1], acc);
            acc = fmaf(__uint_as_float(uu1 << 16),         w[q*8 + 2], acc);
            acc = fmaf(__uint_as_float(uu1 & 0xffff0000u), w[q*8 + 3], acc);
            acc = fmaf(__uint_as_float(uu2 << 16),         w[q*8 + 4], acc);
            acc = fmaf(__uint_as_float(uu2 & 0xffff0000u), w[q*8 + 5], acc);
            acc = fmaf(__uint_as_float(uu3 << 16),         w[q*8 + 6], acc);
            acc = fmaf(__uint_as_float(uu3 & 0xffff0000u), w[q*8 + 7], acc);
        }
        s1 += acc;
        s2 = fmaf(acc, acc, s2);
        mx = fmaxf(mx, acc);
        mn = fminf(mn, acc);
    }
    mxb[(size_t)pt*128 + o] = mx;
    mnb[(size_t)pt*128 + o] = mn;
    psum  [(size_t)pt*128 + o] = s1;
    psumsq[(size_t)pt*128 + o] = s2;
}

// ---------------- deterministic BN stat reduce -> scale/shift ----------------
template<int CO>
__global__ __launch_bounds__(256) void bnred_kernel(const float* __restrict__ psum,
    const float* __restrict__ psumsq, const float* __restrict__ g, const float* __restrict__ beta,
    float* __restrict__ sc, float* __restrict__ sh, int nslots)
{
    const int c = blockIdx.x;
    const int t = threadIdx.x;
    float s1 = 0, s2 = 0;
    for (int i = t; i < nslots; i += 256) {
        s1 += psum  [(size_t)i*CO + c];
        s2 += psumsq[(size_t)i*CO + c];
    }
    __shared__ float a1[256], a2[256];
    a1[t] = s1; a2[t] = s2;
    __syncthreads();
    for (int st = 128; st > 0; st >>= 1) {
        if (t < st) { a1[t] += a1[t+st]; a2[t] += a2[t+st]; }
        __syncthreads();
    }
    if (t == 0) {
        const float invM = 1.0f / (float)M_;
        float mu  = a1[0] * invM;
        float var = fmaxf(a2[0] * invM - mu*mu, 0.f);
        float rs  = 1.0f / sqrtf(var + EPS_);
        float s   = rs * g[c];
        sc[c] = s;
        sh[c] = fmaf(-mu, s, beta[c]);
    }
}

// ---------------- BN3 affine on max/min + ReLU, LDS transpose, write (B,128,NP) f32 ----------------
__global__ __launch_bounds__(256) void final_kernel(const float* __restrict__ mxb,
    const float* __restrict__ mnb, const float* __restrict__ sc, const float* __restrict__ sh,
    float* __restrict__ out)
{
    __shared__ float tile[128][65];
    const int b = blockIdx.y, p0 = blockIdx.x * 64;
    {
        const int o = threadIdx.x & 127, ph = threadIdx.x >> 7;
        const float s = sc[o], h = sh[o];
        const bool pos = (s >= 0.f);
        for (int pl = ph; pl < 64; pl += 2) {
            const size_t pt = (size_t)b*NP_ + p0 + pl;
            float v = pos ? mxb[pt*128 + o] : mnb[pt*128 + o];
            tile[o][pl] = fmaxf(fmaf(v, s, h), 0.f);   // max_s relu(affine) == relu(affine(max/min))
        }
    }
    __syncthreads();
    {
        const int p = threadIdx.x & 63, oh = threadIdx.x >> 6;
        for (int oo = oh; oo < 128; oo += 4)
            out[(size_t)(B_*NP_*3) + ((size_t)(b*128 + oo))*NP_ + p0 + p] = tile[oo][p];
    }
}

// ---------------- launch ----------------
extern "C" void kernel_launch(void* const* d_in, const int* in_sizes, int n_in,
                              void* d_out, int out_size, void* d_ws, size_t ws_size,
                              hipStream_t stream)
{
    const float* xyz  = (const float*)d_in[0];
    const float* feat = (const float*)d_in[1];
    const float* W0   = (const float*)d_in[2];
    const float* b0   = (const float*)d_in[3];
    const float* g0   = (const float*)d_in[4];
    const float* be0  = (const float*)d_in[5];
    const float* W1   = (const float*)d_in[6];
    const float* b1   = (const float*)d_in[7];
    const float* g1   = (const float*)d_in[8];
    const float* be1  = (const float*)d_in[9];
    const float* W2   = (const float*)d_in[10];
    const float* b2   = (const float*)d_in[11];
    const float* g2   = (const float*)d_in[12];
    const float* be2  = (const float*)d_in[13];

    char* ws = (char*)d_ws;                                  // total needed: ~53.1 MB
    int*   fpsidx = (int*)  (ws + 0);                        //  32 KB
    float* newxyz = (float*)(ws + 32768);                    //  96 KB
    int*   ball   = (int*)  (ws + 131072);                   //   1 MB
    float* scb    = (float*)(ws + 1179648);                  //   4 KB
    float* psum   = (float*)(ws + 1183744);                  //   4 MB
    float* psumsq = (float*)(ws + 5378048);                  //   4 MB
    __hip_bfloat16* featT = (__hip_bfloat16*)(ws + 9572352); //   4 MB
    float* mxb    = (float*)(ws + 13766656);                 //   4 MB
    float* mnb    = (float*)(ws + 17960960);                 //   4 MB
    __hip_bfloat16* buf1 = (__hip_bfloat16*)(ws + 22155264); //  32 MB (pre1/act1/pre2/act2 in place)
    float* out = (float*)d_out;                              // reference outputs are float32

    float* sc1 = scb;       float* sh1 = scb + 128;
    float* sc2 = scb + 256; float* sh2 = scb + 384;
    float* sc3 = scb + 512; float* sh3 = scb + 640;

    transpose_kernel<<<dim3(N_/64, B_), 256, 0, stream>>>(feat, featT);
    fps_kernel<<<dim3(B_), 512, 0, stream>>>(xyz, fpsidx, newxyz, out);
    ball_kernel<<<dim3(B_*NP_/4), 256, 0, stream>>>(xyz, newxyz, ball);

    gemm1_kernel<<<1024, 256, 0, stream>>>(xyz, featT, newxyz, ball, W0, b0, buf1, psum, psumsq);
    bnred_kernel<64><<<64, 256, 0, stream>>>(psum, psumsq, g0, be0, sc1, sh1, 4096);
    epi_kernel<<<M_*64/8/256, 256, 0, stream>>>(buf1, sc1, sh1);
    gemm2_kernel<<<1024, 256, 0, stream>>>(buf1, W1, b1, psum, psumsq);
    bnred_kernel<64><<<64, 256, 0, stream>>>(psum, psumsq, g1, be1, sc2, sh2, 4096);
    epi_kernel<<<M_*64/8/256, 256, 0, stream>>>(buf1, sc2, sh2);
    gemm3_kernel<<<4096, 256, 0, stream>>>(buf1, W2, b2, mxb, mnb, psum, psumsq);
    bnred_kernel<128><<<128, 256, 0, stream>>>(psum, psumsq, g2, be2, sc3, sh3, 8192);
    final_kernel<<<dim3(NP_/64, B_), 256, 0, stream>>>(mxb, mnb, sc3, sh3, out);
}